// Round 1
// baseline (2003.586 us; speedup 1.0000x reference)
//
#include <hip/hip_runtime.h>
#include <stdint.h>

// Tomography: sinogram[b,a,d] = sum_p A[a*129+d, p] * I_pad[b, p]
// A is a binary ray mask; detector spacing is exactly 1.0, band width 1.0,
// so per (angle, pixel) at most ONE detector is hit, and it lies within
// round(r) +/- 1 of r = cos(th)*X + sin(th)*Y (window tolerates |r_ours -
// r_jax| < 1; actual difference is <1e-3). We read the actual A bits for the
// 3 candidates, so the mask matches the reference EXACTLY regardless of how
// JAX computed cos/sin/linspace. Padding pixels are zero -> only the central
// 64x64 image contributes.

#define TDIM 64
#define TPAD 32
#define PSIDE 128          // padded side = 2*dim
#define NANG 180
#define NDET 129           // dim + 2*pad + 1
#define NPIX 4096          // 64*64 central pixels
#define NCOPY 16           // replicated LDS accumulators (atomic-conflict fix)
#define ASTRIDE 137        // 129 padded; +9 banks rotation per copy

__global__ __launch_bounds__(256)
void tomo_kernel(const float* __restrict__ I, const float* __restrict__ A,
                 float* __restrict__ out) {
    __shared__ float acc[NCOPY * ASTRIDE];
    __shared__ float cs[2];
    const int a = blockIdx.x;      // angle
    const int b = blockIdx.y;      // batch
    const int tid = threadIdx.x;

    if (tid == 0) {
        // theta = linspace(0, 2*pi, 180)[a]; double precision keeps us within
        // ~1e-7 of JAX's value -> candidate window is provably sufficient.
        double th = (2.0 * 3.14159265358979323846) * (double)a / 179.0;
        cs[0] = (float)cos(th);
        cs[1] = (float)sin(th);
    }
    for (int k = tid; k < NCOPY * ASTRIDE; k += 256) acc[k] = 0.0f;
    __syncthreads();

    const float c = cs[0], s = cs[1];
    const float* Ib = I + (size_t)b * NPIX;
    float* myacc = &acc[(tid & (NCOPY - 1)) * ASTRIDE];

    // Each wave handles one full image row per iteration (64 pixels = 1 row).
    #pragma unroll
    for (int it = 0; it < NPIX / 256; ++it) {
        const int p = tid + it * 256;
        const int i = p >> 6;           // image row   (X axis, varies 1st)
        const int j = p & 63;           // image col   (Y axis)
        const float v = Ib[p];
        const float r = c * (float)(i - TPAD) + s * (float)(j - TPAD);
        const int d0 = (int)floorf(r + 0.5f) + TDIM;   // nearest detector
        const int pp = (i + TPAD) * PSIDE + (j + TPAD); // padded pixel index
        int dsel = -1;
        #pragma unroll
        for (int o = -1; o <= 1; ++o) {
            const int dd = d0 + o;
            if (dd >= 0 && dd < NDET) {
                const float av = A[((size_t)a * NDET + (size_t)dd) * (PSIDE * PSIDE) + pp];
                if (av > 0.5f) dsel = dd;   // at most one candidate is set
            }
        }
        if (dsel >= 0) atomicAdd(&myacc[dsel], v);
    }
    __syncthreads();

    // Reduce the 16 replicas; write all 129 detectors (poison-safe).
    for (int d = tid; d < NDET; d += 256) {
        float sum = 0.0f;
        #pragma unroll
        for (int k = 0; k < NCOPY; ++k) sum += acc[k * ASTRIDE + d];
        out[(size_t)b * (NANG * NDET) + (size_t)a * NDET + d] = sum;
    }
}

extern "C" void kernel_launch(void* const* d_in, const int* in_sizes, int n_in,
                              void* d_out, int out_size, void* d_ws, size_t ws_size,
                              hipStream_t stream) {
    const float* I = (const float*)d_in[0];   // [B,1,64,64] fp32
    const float* A = (const float*)d_in[1];   // [23220, 16384] fp32 binary
    float* out = (float*)d_out;               // [B,1,180,129] fp32
    const int B = in_sizes[0] / NPIX;         // 32
    dim3 grid(NANG, B);
    tomo_kernel<<<grid, 256, 0, stream>>>(I, A, out);
}

// Round 3
// 1706.939 us; speedup vs baseline: 1.1738x; 1.1738x over previous
//
#include <hip/hip_runtime.h>
#include <stdint.h>

// Tomography sinogram via sparse delta-ray structure.
//
// sinogram[b,a,d] = sum_p A[a*129+d, p] * I_pad[b, p]; A is a binary ray
// mask with detector spacing exactly 1.0 and band width 1.0 (strict <0.5),
// so each (angle, pixel) hits AT MOST ONE detector, which lies within
// round(r)+/-1 of r = cos(th)*X + sin(th)*Y. We read A's actual bits for
// the 3 candidates, so the mask matches the JAX reference exactly no matter
// how cos/sin/linspace were rounded. Pad pixels are zero -> only the
// central 64x64 contributes.
//
// Phase 1 builds a per-(angle,pixel) uint8 detector map ONCE (batch-
// independent; previously recomputed 32x). Phase 2 gathers image values by
// map with vectorized loads + run-length-merged LDS atomics.

#define TDIM 64
#define TPAD 32
#define PSIDE 128          // padded side = 2*dim
#define NANG 180
#define NDET 129           // dim + 2*pad + 1
#define NPIX 4096          // 64*64 central pixels
#define NCOPY 16           // replicated LDS accumulators (conflict fix)
#define ASTRIDE 137        // 129 padded; rotates banks per copy
#define NOHIT 255

// ---- Phase 1: detector map. grid (180, 16), 256 thr, 1 pixel/thread. ----
__global__ __launch_bounds__(256)
void tomo_map_kernel(const float* __restrict__ A, uint8_t* __restrict__ map) {
    __shared__ float cs[2];
    const int a = blockIdx.x;
    const int p = blockIdx.y * 256 + threadIdx.x;
    if (threadIdx.x == 0) {
        // linspace(0, 2*pi, 180)[a] in double: |r_ours - r_jax| < 1e-4,
        // candidate window tolerates < ~1.0.
        double th = (2.0 * 3.14159265358979323846) * (double)a / 179.0;
        cs[0] = (float)cos(th);
        cs[1] = (float)sin(th);
    }
    __syncthreads();
    const int i = p >> 6;                    // X index (varies along axis 0)
    const int j = p & 63;                    // Y index
    const float r = cs[0] * (float)(i - TPAD) + cs[1] * (float)(j - TPAD);
    const int d0 = (int)floorf(r + 0.5f) + TDIM;
    const int pp = (i + TPAD) * PSIDE + (j + TPAD);
    int dsel = NOHIT;
    #pragma unroll
    for (int o = -1; o <= 1; ++o) {
        const int dd = d0 + o;
        if (dd >= 0 && dd < NDET) {
            const float av = A[((size_t)a * NDET + (size_t)dd) * (PSIDE * PSIDE) + pp];
            if (av > 0.5f) dsel = dd;        // at most one candidate is set
        }
    }
    map[a * NPIX + p] = (uint8_t)dsel;
}

// ---- Phase 2: accumulate. grid (180, 32), 256 thr, 16 pixels/thread. ----
__global__ __launch_bounds__(256)
void tomo_acc_kernel(const float* __restrict__ I, const uint8_t* __restrict__ map,
                     float* __restrict__ out) {
    __shared__ float acc[NCOPY * ASTRIDE];
    const int a = blockIdx.x;
    const int b = blockIdx.y;
    const int tid = threadIdx.x;

    for (int k = tid; k < NCOPY * ASTRIDE; k += 256) acc[k] = 0.0f;
    __syncthreads();

    const float*  Ib = I + (size_t)b * NPIX;
    const uint8_t* mp = map + a * NPIX;
    float* myacc = &acc[(tid & (NCOPY - 1)) * ASTRIDE];

    #pragma unroll
    for (int it = 0; it < NPIX / 1024; ++it) {          // 4 iterations
        const int p = it * 1024 + tid * 4;              // 16B-aligned
        const uchar4 d4 = *(const uchar4*)(mp + p);
        const float4 v4 = *(const float4*)(Ib + p);
        // Run-length merge: consecutive pixels along j often share a
        // detector (always, at axis-aligned angles) -> fewer atomics.
        int   rund = d4.x;
        float runv = v4.x;
        const int   dn[3] = { d4.y, d4.z, d4.w };
        const float vn[3] = { v4.y, v4.z, v4.w };
        #pragma unroll
        for (int k = 0; k < 3; ++k) {
            if (dn[k] == rund) {
                runv += vn[k];
            } else {
                if (rund < NDET) atomicAdd(&myacc[rund], runv);
                rund = dn[k];
                runv = vn[k];
            }
        }
        if (rund < NDET) atomicAdd(&myacc[rund], runv);
    }
    __syncthreads();

    // Reduce 16 replicas; write all 129 detectors (poison-safe).
    for (int d = tid; d < NDET; d += 256) {
        float sum = 0.0f;
        #pragma unroll
        for (int k = 0; k < NCOPY; ++k) sum += acc[k * ASTRIDE + d];
        out[((size_t)b * NANG + (size_t)a) * NDET + d] = sum;
    }
}

extern "C" void kernel_launch(void* const* d_in, const int* in_sizes, int n_in,
                              void* d_out, int out_size, void* d_ws, size_t ws_size,
                              hipStream_t stream) {
    const float* I = (const float*)d_in[0];   // [B,1,64,64] fp32
    const float* A = (const float*)d_in[1];   // [23220, 16384] fp32 binary
    float* out = (float*)d_out;               // [B,1,180,129] fp32
    uint8_t* map = (uint8_t*)d_ws;            // 180*4096 = 737,280 B
    const int B = in_sizes[0] / NPIX;         // 32

    tomo_map_kernel<<<dim3(NANG, 16), 256, 0, stream>>>(A, map);
    tomo_acc_kernel<<<dim3(NANG, B), 256, 0, stream>>>(I, map, out);
}